// Round 7
// baseline (139.988 us; speedup 1.0000x reference)
//
#include <hip/hip_runtime.h>
#include <hip/hip_bf16.h>

// SimCLR NT-Xent loss v7: occupancy push — 2-buffer LDS ring (32 KB),
// NSPLIT=32 (1024 blocks = 4/CU), __launch_bounds__(256,4) => VGPR<=128
// => 4 waves/SIMD. Depth-1 counted-vmcnt prefetch, direct smem MFMA feeds.

#define NROWS 4096
#define DDIM  512
#define NSPLIT 32                // column splits
#define QCOLS (NROWS / NSPLIT)   // 128 cols per split
#define NT (QCOLS / 16)          // 8 column tiles per block
#define BM 128                   // rows per block (4 waves x 32)
#define NEG_BIG (-3.0e38f)
#define SQRT_CSCALE 3.798282562f // sqrt(10*log2(e)); (sqrt(c)A)(sqrt(c)B) = c*sim
#define LN2 0.69314718055994530942f
#define THR 40.0f                // defer-max threshold (log2 units)

typedef __bf16 bf16x8 __attribute__((ext_vector_type(8)));
typedef float  f32x4  __attribute__((ext_vector_type(4)));

#define GLOAD_LDS16(g, l) __builtin_amdgcn_global_load_lds(                    \
    (const __attribute__((address_space(1))) void*)(g),                        \
    (__attribute__((address_space(3))) void*)(l), 16, 0, 0)

#define MFMA16(a, b, c) __builtin_amdgcn_mfma_f32_16x16x32_bf16((a), (b), (c), 0, 0, 0)

// ---------------- kernel 0: fp32 -> bf16, scaled by sqrt(c) ----------------
__global__ void jl_cvt(const float* __restrict__ in, __bf16* __restrict__ out) {
    int i = (blockIdx.x * 256 + threadIdx.x) * 8;
    float4 a = *(const float4*)(in + i);
    float4 b = *(const float4*)(in + i + 4);
    bf16x8 w;
    w[0] = (__bf16)(a.x * SQRT_CSCALE); w[1] = (__bf16)(a.y * SQRT_CSCALE);
    w[2] = (__bf16)(a.z * SQRT_CSCALE); w[3] = (__bf16)(a.w * SQRT_CSCALE);
    w[4] = (__bf16)(b.x * SQRT_CSCALE); w[5] = (__bf16)(b.y * SQRT_CSCALE);
    w[6] = (__bf16)(b.z * SQRT_CSCALE); w[7] = (__bf16)(b.w * SQRT_CSCALE);
    *(bf16x8*)(out + i) = w;
}

// ---------------- kernel 1: fused GEMM + online log2-sum-exp2 partials ----------------
// grid = (NROWS/BM) * NSPLIT = 32*32 = 1024 blocks (4/CU), 256 threads (4 waves).
// block: rows [rbk*128, +128), cols [q*128, +128). wave w: rows [.. + 32w, +32)
__global__ __launch_bounds__(256, 4) void jl_main(const __bf16* __restrict__ rb,
                                                  float* __restrict__ pm,
                                                  float* __restrict__ ps,
                                                  float* __restrict__ pos) {
    __shared__ bf16x8 smem[2][16][64];   // 2-buffer ring, fragment-ordered, 32 KB

    const int rbk  = blockIdx.x >> 5;   // 0..31
    const int q    = blockIdx.x & 31;   // 0..31
    const int wave = threadIdx.x >> 6;
    const int lane = threadIdx.x & 63;

    const int row0 = rbk * BM + wave * 32;   // wave's first row (32 rows)
    const int col0 = q * QCOLS;
    const int lrow = lane & 15;
    const int lk   = lane >> 4;

    // A fragments, two 16-row halves: 32 x bf16x8 = 64 VGPR
    bf16x8 afA[16], afB[16];
    {
        const __bf16* arow = rb + (size_t)(row0 + lrow) * DDIM + lk * 8;
        #pragma unroll
        for (int kb = 0; kb < 16; ++kb) {
            afA[kb] = *(const bf16x8*)(arow + kb * 32);
            afB[kb] = *(const bf16x8*)(arow + 16 * DDIM + kb * 32);
        }
    }

    // per-lane fragment-ordered global source for B staging
    const __bf16* gB = rb + (size_t)(col0 + lrow) * DDIM + lk * 8;

    // wave w stages kb = 4w..4w+3 of each tile (4 gload_lds per wave per tile)
#define STAGE(T)                                                               \
    do {                                                                       \
        const __bf16* g_ = gB + (size_t)(T) * 16 * DDIM;                       \
        _Pragma("unroll")                                                      \
        for (int i_ = 0; i_ < 4; ++i_) {                                       \
            int kb_ = wave * 4 + i_;                                           \
            GLOAD_LDS16(g_ + kb_ * 32, &smem[(T) & 1][kb_][0]);                \
        }                                                                      \
    } while (0)

    STAGE(0);

    float m[2][4], s[2][4];
    #pragma unroll
    for (int h = 0; h < 2; ++h)
        #pragma unroll
        for (int r = 0; r < 4; ++r) { m[h][r] = NEG_BIG; s[h][r] = 0.0f; }

    for (int jt = 0; jt < NT; ++jt) {
        if (jt + 1 < NT) STAGE(jt + 1);

        // counted vmcnt: wait for tile jt's 4 loads; jt+1's stay in flight
        if (jt < NT - 1) asm volatile("s_waitcnt vmcnt(4)" ::: "memory");
        else             asm volatile("s_waitcnt vmcnt(0)" ::: "memory");
        __builtin_amdgcn_s_barrier();
        __builtin_amdgcn_sched_barrier(0);

        const int cb = jt & 1;

        f32x4 accA0 = {0.f,0.f,0.f,0.f}, accA1 = {0.f,0.f,0.f,0.f};
        f32x4 accB0 = {0.f,0.f,0.f,0.f}, accB1 = {0.f,0.f,0.f,0.f};
        __builtin_amdgcn_s_setprio(1);
        #pragma unroll
        for (int kb = 0; kb < 16; ++kb) {
            bf16x8 bf = smem[cb][kb][lane];
            if (kb & 1) {
                accA1 = MFMA16(afA[kb], bf, accA1);
                accB1 = MFMA16(afB[kb], bf, accB1);
            } else {
                accA0 = MFMA16(afA[kb], bf, accA0);
                accB0 = MFMA16(afB[kb], bf, accB0);
            }
        }
        __builtin_amdgcn_s_setprio(0);

        f32x4 y[2];
        y[0] = accA0 + accA1;   // rows row0    + 4*lk + r, col col0+jt*16+lrow
        y[1] = accB0 + accB1;   // rows row0+16 + 4*lk + r

        const int ctile = col0 + jt * 16;   // wave-uniform

        // positive-pair tiles (uniform, rare): partner of row i is i^2048
        if (ctile == (row0 ^ 2048)) {
            #pragma unroll
            for (int r = 0; r < 4; ++r)
                if (lrow == 4 * lk + r) pos[row0 + 4 * lk + r] = y[0][r];
        }
        if (ctile == ((row0 + 16) ^ 2048)) {
            #pragma unroll
            for (int r = 0; r < 4; ++r)
                if (lrow == 4 * lk + r) pos[row0 + 16 + 4 * lk + r] = y[1][r];
        }

        const bool d0 = (ctile == row0), d1 = (ctile == row0 + 16);
        if (d0 || d1) {
            // diagonal tile (rare): masked full online update
            #pragma unroll
            for (int h = 0; h < 2; ++h) {
                const bool dh = h ? d1 : d0;
                #pragma unroll
                for (int r = 0; r < 4; ++r) {
                    const bool isd = dh && (lrow == 4 * lk + r);
                    float yv = isd ? NEG_BIG : y[h][r];
                    float mn = fmaxf(m[h][r], yv);
                    float e  = isd ? 0.0f : __builtin_amdgcn_exp2f(yv - mn);
                    s[h][r] = s[h][r] * __builtin_amdgcn_exp2f(m[h][r] - mn) + e;
                    m[h][r] = mn;
                }
            }
        } else {
            float t0 = y[0][0] - m[0][0], t1 = y[0][1] - m[0][1];
            float t2 = y[0][2] - m[0][2], t3 = y[0][3] - m[0][3];
            float t4 = y[1][0] - m[1][0], t5 = y[1][1] - m[1][1];
            float t6 = y[1][2] - m[1][2], t7 = y[1][3] - m[1][3];
            float dmax = fmaxf(fmaxf(fmaxf(t0, t1), fmaxf(t2, t3)),
                               fmaxf(fmaxf(t4, t5), fmaxf(t6, t7)));
            if (__any(dmax > THR)) {
                #pragma unroll
                for (int h = 0; h < 2; ++h)
                    #pragma unroll
                    for (int r = 0; r < 4; ++r) {
                        float mn = fmaxf(m[h][r], y[h][r]);
                        s[h][r] = s[h][r] * __builtin_amdgcn_exp2f(m[h][r] - mn)
                                + __builtin_amdgcn_exp2f(y[h][r] - mn);
                        m[h][r] = mn;
                    }
            } else {
                s[0][0] += __builtin_amdgcn_exp2f(t0);
                s[0][1] += __builtin_amdgcn_exp2f(t1);
                s[0][2] += __builtin_amdgcn_exp2f(t2);
                s[0][3] += __builtin_amdgcn_exp2f(t3);
                s[1][0] += __builtin_amdgcn_exp2f(t4);
                s[1][1] += __builtin_amdgcn_exp2f(t5);
                s[1][2] += __builtin_amdgcn_exp2f(t6);
                s[1][3] += __builtin_amdgcn_exp2f(t7);
            }
        }
    }
#undef STAGE

    // merge (m,s) across the 16 lanes of each row group, write partials
    #pragma unroll
    for (int h = 0; h < 2; ++h)
        #pragma unroll
        for (int r = 0; r < 4; ++r) {
            float mm = m[h][r], ss = s[h][r];
            #pragma unroll
            for (int off = 1; off < 16; off <<= 1) {
                float mo = __shfl_xor(mm, off, 64);
                float so = __shfl_xor(ss, off, 64);
                float mn = fmaxf(mm, mo);
                ss = ss * __builtin_amdgcn_exp2f(mm - mn)
                   + so * __builtin_amdgcn_exp2f(mo - mn);
                mm = mn;
            }
            if (lrow == 0) {
                const int grow = row0 + 16 * h + 4 * lk + r;
                pm[grow * NSPLIT + q] = mm;
                ps[grow * NSPLIT + q] = ss;
            }
        }
}

// ---------------- kernel 2a: per-row loss + per-block partial sum ----------------
__global__ void jl_rowloss(const float* __restrict__ pm, const float* __restrict__ ps,
                           const float* __restrict__ pos, float* __restrict__ part) {
    __shared__ float red[256];
    const int t = threadIdx.x;
    const int row = blockIdx.x * 256 + t;
    float mb = NEG_BIG;
    #pragma unroll
    for (int qq = 0; qq < NSPLIT; ++qq) mb = fmaxf(mb, pm[row * NSPLIT + qq]);
    float st = 0.0f;
    #pragma unroll
    for (int qq = 0; qq < NSPLIT; ++qq)
        st += ps[row * NSPLIT + qq] * __builtin_amdgcn_exp2f(pm[row * NSPLIT + qq] - mb);
    // per-row loss in log2 units: mb + log2(st) - pos
    red[t] = mb + __builtin_amdgcn_logf(st) - pos[row];
    __syncthreads();
    for (int off = 128; off > 0; off >>= 1) {
        if (t < off) red[t] += red[t + off];
        __syncthreads();
    }
    if (t == 0) part[blockIdx.x] = red[0];
}

// ---------------- kernel 2b: final reduce ----------------
__global__ void jl_final(const float* __restrict__ part, float* __restrict__ out) {
    const int t = threadIdx.x;
    float v = (t < NROWS / 256) ? part[t] : 0.0f;
    #pragma unroll
    for (int off = 1; off < 16; off <<= 1) v += __shfl_xor(v, off, 64);
    if (t == 0) out[0] = v * (LN2 / (float)NROWS);
}

extern "C" void kernel_launch(void* const* d_in, const int* in_sizes, int n_in,
                              void* d_out, int out_size, void* d_ws, size_t ws_size,
                              hipStream_t stream) {
    const float* rep = (const float*)d_in[0];
    float* out = (float*)d_out;

    // workspace layout: rbuf 4MB | pm | ps | pos | part
    __bf16* rbuf = (__bf16*)d_ws;
    float*  pm   = (float*)(rbuf + (size_t)NROWS * DDIM);
    float*  ps   = pm + NROWS * NSPLIT;
    float*  pos  = ps + NROWS * NSPLIT;
    float*  part = pos + NROWS;

    jl_cvt<<<(NROWS * DDIM) / (256 * 8), 256, 0, stream>>>(rep, rbuf);
    jl_main<<<(NROWS / BM) * NSPLIT, 256, 0, stream>>>(rbuf, pm, ps, pos);
    jl_rowloss<<<NROWS / 256, 256, 0, stream>>>(pm, ps, pos, part);
    jl_final<<<1, 64, 0, stream>>>(part, out);
}

// Round 8
// 65.530 us; speedup vs baseline: 2.1363x; 2.1363x over previous
//
#include <hip/hip_runtime.h>
#include <hip/hip_bf16.h>

// SimCLR NT-Xent loss v8: 3 blocks/CU via uneven 24-way column split
// (768 blocks = exactly 3/CU, 12 waves/CU), __launch_bounds__(256,3) so no
// spill (R7 lesson: (256,4) => 128-reg cap => 73MB scratch churn).
// R6 core kept: 2-buffer LDS ring, counted vmcnt depth-1, 1 barrier/tile.

#define NROWS 4096
#define DDIM  512
#define NSPLIT 24                // uneven splits: 16 x 11 tiles + 8 x 10 tiles
#define BM 128                   // rows per block (4 waves x 32)
#define NEG_BIG (-3.0e38f)
#define SQRT_CSCALE 3.798282562f // sqrt(10*log2(e)); (sqrt(c)A)(sqrt(c)B) = c*sim
#define LN2 0.69314718055994530942f
#define THR 40.0f                // defer-max threshold (log2 units)

typedef __bf16 bf16x8 __attribute__((ext_vector_type(8)));
typedef float  f32x4  __attribute__((ext_vector_type(4)));

#define GLOAD_LDS16(g, l) __builtin_amdgcn_global_load_lds(                    \
    (const __attribute__((address_space(1))) void*)(g),                        \
    (__attribute__((address_space(3))) void*)(l), 16, 0, 0)

#define MFMA16(a, b, c) __builtin_amdgcn_mfma_f32_16x16x32_bf16((a), (b), (c), 0, 0, 0)

// ---------------- kernel 0: fp32 -> bf16, scaled by sqrt(c) ----------------
__global__ void jl_cvt(const float* __restrict__ in, __bf16* __restrict__ out) {
    int i = (blockIdx.x * 256 + threadIdx.x) * 8;
    float4 a = *(const float4*)(in + i);
    float4 b = *(const float4*)(in + i + 4);
    bf16x8 w;
    w[0] = (__bf16)(a.x * SQRT_CSCALE); w[1] = (__bf16)(a.y * SQRT_CSCALE);
    w[2] = (__bf16)(a.z * SQRT_CSCALE); w[3] = (__bf16)(a.w * SQRT_CSCALE);
    w[4] = (__bf16)(b.x * SQRT_CSCALE); w[5] = (__bf16)(b.y * SQRT_CSCALE);
    w[6] = (__bf16)(b.z * SQRT_CSCALE); w[7] = (__bf16)(b.w * SQRT_CSCALE);
    *(bf16x8*)(out + i) = w;
}

// ---------------- kernel 1: fused GEMM + online log2-sum-exp2 partials ----------------
// grid = 32 rowblocks * 24 splits = 768 blocks (3/CU), 256 threads (4 waves).
// split q tiles: q<16 -> [11q, 11q+11), else [176+10(q-16), +10)  (16-col tiles)
__global__ __launch_bounds__(256, 3) void jl_main(const __bf16* __restrict__ rb,
                                                  float* __restrict__ pm,
                                                  float* __restrict__ ps,
                                                  float* __restrict__ pos) {
    __shared__ bf16x8 smem[2][16][64];   // 2-buffer ring, fragment-ordered, 32 KB

    const int rbk  = blockIdx.x / NSPLIT;   // 0..31
    const int q    = blockIdx.x % NSPLIT;   // 0..23
    const int tile0 = (q < 16) ? 11 * q : 176 + 10 * (q - 16);
    const int NT    = (q < 16) ? 11 : 10;

    const int wave = threadIdx.x >> 6;
    const int lane = threadIdx.x & 63;

    const int row0 = rbk * BM + wave * 32;   // wave's first row (32 rows)
    const int lrow = lane & 15;
    const int lk   = lane >> 4;

    // A fragments, two 16-row halves: 32 x bf16x8 (64 regs, AGPR-eligible)
    bf16x8 afA[16], afB[16];
    {
        const __bf16* arow = rb + (size_t)(row0 + lrow) * DDIM + lk * 8;
        #pragma unroll
        for (int kb = 0; kb < 16; ++kb) {
            afA[kb] = *(const bf16x8*)(arow + kb * 32);
            afB[kb] = *(const bf16x8*)(arow + 16 * DDIM + kb * 32);
        }
    }

    // per-lane fragment-ordered global source for B staging (tile t = tile0+jt)
    const __bf16* gB = rb + (size_t)(tile0 * 16 + lrow) * DDIM + lk * 8;

    // wave w stages kb = 4w..4w+3 of each tile (4 gload_lds per wave per tile)
#define STAGE(J)                                                               \
    do {                                                                       \
        const __bf16* g_ = gB + (size_t)(J) * 16 * DDIM;                       \
        _Pragma("unroll")                                                      \
        for (int i_ = 0; i_ < 4; ++i_) {                                       \
            int kb_ = wave * 4 + i_;                                           \
            GLOAD_LDS16(g_ + kb_ * 32, &smem[(J) & 1][kb_][0]);                \
        }                                                                      \
    } while (0)

    STAGE(0);

    float m[2][4], s[2][4];
    #pragma unroll
    for (int h = 0; h < 2; ++h)
        #pragma unroll
        for (int r = 0; r < 4; ++r) { m[h][r] = NEG_BIG; s[h][r] = 0.0f; }

    for (int jt = 0; jt < NT; ++jt) {
        if (jt + 1 < NT) STAGE(jt + 1);

        // counted vmcnt: wait for tile jt's 4 loads; jt+1's stay in flight
        if (jt < NT - 1) asm volatile("s_waitcnt vmcnt(4)" ::: "memory");
        else             asm volatile("s_waitcnt vmcnt(0)" ::: "memory");
        __builtin_amdgcn_s_barrier();
        __builtin_amdgcn_sched_barrier(0);

        const int cb = jt & 1;

        f32x4 accA0 = {0.f,0.f,0.f,0.f}, accA1 = {0.f,0.f,0.f,0.f};
        f32x4 accB0 = {0.f,0.f,0.f,0.f}, accB1 = {0.f,0.f,0.f,0.f};
        __builtin_amdgcn_s_setprio(1);
        #pragma unroll
        for (int kb = 0; kb < 16; ++kb) {
            bf16x8 bf = smem[cb][kb][lane];
            if (kb & 1) {
                accA1 = MFMA16(afA[kb], bf, accA1);
                accB1 = MFMA16(afB[kb], bf, accB1);
            } else {
                accA0 = MFMA16(afA[kb], bf, accA0);
                accB0 = MFMA16(afB[kb], bf, accB0);
            }
        }
        __builtin_amdgcn_s_setprio(0);

        f32x4 y[2];
        y[0] = accA0 + accA1;   // rows row0    + 4*lk + r, col ctile+lrow
        y[1] = accB0 + accB1;   // rows row0+16 + 4*lk + r

        const int ctile = (tile0 + jt) * 16;   // wave-uniform absolute column

        // positive-pair tiles (uniform, rare): partner of row i is i^2048
        if (ctile == (row0 ^ 2048)) {
            #pragma unroll
            for (int r = 0; r < 4; ++r)
                if (lrow == 4 * lk + r) pos[row0 + 4 * lk + r] = y[0][r];
        }
        if (ctile == ((row0 + 16) ^ 2048)) {
            #pragma unroll
            for (int r = 0; r < 4; ++r)
                if (lrow == 4 * lk + r) pos[row0 + 16 + 4 * lk + r] = y[1][r];
        }

        const bool d0 = (ctile == row0), d1 = (ctile == row0 + 16);
        if (d0 || d1) {
            // diagonal tile (rare): masked full online update
            #pragma unroll
            for (int h = 0; h < 2; ++h) {
                const bool dh = h ? d1 : d0;
                #pragma unroll
                for (int r = 0; r < 4; ++r) {
                    const bool isd = dh && (lrow == 4 * lk + r);
                    float yv = isd ? NEG_BIG : y[h][r];
                    float mn = fmaxf(m[h][r], yv);
                    float e  = isd ? 0.0f : __builtin_amdgcn_exp2f(yv - mn);
                    s[h][r] = s[h][r] * __builtin_amdgcn_exp2f(m[h][r] - mn) + e;
                    m[h][r] = mn;
                }
            }
        } else {
            float t0 = y[0][0] - m[0][0], t1 = y[0][1] - m[0][1];
            float t2 = y[0][2] - m[0][2], t3 = y[0][3] - m[0][3];
            float t4 = y[1][0] - m[1][0], t5 = y[1][1] - m[1][1];
            float t6 = y[1][2] - m[1][2], t7 = y[1][3] - m[1][3];
            float dmax = fmaxf(fmaxf(fmaxf(t0, t1), fmaxf(t2, t3)),
                               fmaxf(fmaxf(t4, t5), fmaxf(t6, t7)));
            if (__any(dmax > THR)) {
                #pragma unroll
                for (int h = 0; h < 2; ++h)
                    #pragma unroll
                    for (int r = 0; r < 4; ++r) {
                        float mn = fmaxf(m[h][r], y[h][r]);
                        s[h][r] = s[h][r] * __builtin_amdgcn_exp2f(m[h][r] - mn)
                                + __builtin_amdgcn_exp2f(y[h][r] - mn);
                        m[h][r] = mn;
                    }
            } else {
                s[0][0] += __builtin_amdgcn_exp2f(t0);
                s[0][1] += __builtin_amdgcn_exp2f(t1);
                s[0][2] += __builtin_amdgcn_exp2f(t2);
                s[0][3] += __builtin_amdgcn_exp2f(t3);
                s[1][0] += __builtin_amdgcn_exp2f(t4);
                s[1][1] += __builtin_amdgcn_exp2f(t5);
                s[1][2] += __builtin_amdgcn_exp2f(t6);
                s[1][3] += __builtin_amdgcn_exp2f(t7);
            }
        }
    }
#undef STAGE

    // merge (m,s) across the 16 lanes of each row group, write partials
    #pragma unroll
    for (int h = 0; h < 2; ++h)
        #pragma unroll
        for (int r = 0; r < 4; ++r) {
            float mm = m[h][r], ss = s[h][r];
            #pragma unroll
            for (int off = 1; off < 16; off <<= 1) {
                float mo = __shfl_xor(mm, off, 64);
                float so = __shfl_xor(ss, off, 64);
                float mn = fmaxf(mm, mo);
                ss = ss * __builtin_amdgcn_exp2f(mm - mn)
                   + so * __builtin_amdgcn_exp2f(mo - mn);
                mm = mn;
            }
            if (lrow == 0) {
                const int grow = row0 + 16 * h + 4 * lk + r;
                pm[grow * NSPLIT + q] = mm;
                ps[grow * NSPLIT + q] = ss;
            }
        }
}

// ---------------- kernel 2a: per-row loss + per-block partial sum ----------------
__global__ void jl_rowloss(const float* __restrict__ pm, const float* __restrict__ ps,
                           const float* __restrict__ pos, float* __restrict__ part) {
    __shared__ float red[256];
    const int t = threadIdx.x;
    const int row = blockIdx.x * 256 + t;
    float mb = NEG_BIG;
    #pragma unroll
    for (int qq = 0; qq < NSPLIT; ++qq) mb = fmaxf(mb, pm[row * NSPLIT + qq]);
    float st = 0.0f;
    #pragma unroll
    for (int qq = 0; qq < NSPLIT; ++qq)
        st += ps[row * NSPLIT + qq] * __builtin_amdgcn_exp2f(pm[row * NSPLIT + qq] - mb);
    // per-row loss in log2 units: mb + log2(st) - pos
    red[t] = mb + __builtin_amdgcn_logf(st) - pos[row];
    __syncthreads();
    for (int off = 128; off > 0; off >>= 1) {
        if (t < off) red[t] += red[t + off];
        __syncthreads();
    }
    if (t == 0) part[blockIdx.x] = red[0];
}

// ---------------- kernel 2b: final reduce ----------------
__global__ void jl_final(const float* __restrict__ part, float* __restrict__ out) {
    const int t = threadIdx.x;
    float v = (t < NROWS / 256) ? part[t] : 0.0f;
    #pragma unroll
    for (int off = 1; off < 16; off <<= 1) v += __shfl_xor(v, off, 64);
    if (t == 0) out[0] = v * (LN2 / (float)NROWS);
}

extern "C" void kernel_launch(void* const* d_in, const int* in_sizes, int n_in,
                              void* d_out, int out_size, void* d_ws, size_t ws_size,
                              hipStream_t stream) {
    const float* rep = (const float*)d_in[0];
    float* out = (float*)d_out;

    // workspace layout: rbuf 4MB | pm | ps | pos | part
    __bf16* rbuf = (__bf16*)d_ws;
    float*  pm   = (float*)(rbuf + (size_t)NROWS * DDIM);
    float*  ps   = pm + NROWS * NSPLIT;
    float*  pos  = ps + NROWS * NSPLIT;
    float*  part = pos + NROWS;

    jl_cvt<<<(NROWS * DDIM) / (256 * 8), 256, 0, stream>>>(rep, rbuf);
    jl_main<<<32 * NSPLIT, 256, 0, stream>>>(rbuf, pm, ps, pos);
    jl_rowloss<<<NROWS / 256, 256, 0, stream>>>(pm, ps, pos, part);
    jl_final<<<1, 64, 0, stream>>>(part, out);
}

// Round 9
// 42.009 us; speedup vs baseline: 3.3324x; 1.5599x over previous
//
#include <hip/hip_runtime.h>
#include <hip/hip_bf16.h>

// SimCLR NT-Xent loss v9: coalesced B staging (full-1KB-row gload_lds with
// pre-swizzled per-lane global source, T2 XOR swizzle on LDS reads), 32-col
// full-K tiles (single accumulation per tile, epilogue once), race-free
// 2-phase schedule (vmcnt(0) -> barrier -> STAGE -> compute), (256,2).

#define NROWS 4096
#define DDIM  512
#define NSPLIT 16                // column splits (256 cols each)
#define NT 8                     // 8 tiles of 32 cols per block
#define BM 128                   // rows per block (4 waves x 32)
#define NEG_BIG (-3.0e38f)
#define SQRT_CSCALE 3.798282562f // sqrt(10*log2(e)); (sqrt(c)A)(sqrt(c)B) = c*sim
#define LN2 0.69314718055994530942f
#define THR 40.0f                // defer-max threshold (log2 units)

typedef __bf16 bf16x8 __attribute__((ext_vector_type(8)));
typedef float  f32x4  __attribute__((ext_vector_type(4)));

#define GLOAD_LDS16(g, l) __builtin_amdgcn_global_load_lds(                    \
    (const __attribute__((address_space(1))) void*)(g),                        \
    (__attribute__((address_space(3))) void*)(l), 16, 0, 0)

#define MFMA16(a, b, c) __builtin_amdgcn_mfma_f32_16x16x32_bf16((a), (b), (c), 0, 0, 0)

// ---------------- kernel 0: fp32 -> bf16, scaled by sqrt(c) ----------------
__global__ void jl_cvt(const float* __restrict__ in, __bf16* __restrict__ out) {
    int i = (blockIdx.x * 256 + threadIdx.x) * 8;
    float4 a = *(const float4*)(in + i);
    float4 b = *(const float4*)(in + i + 4);
    bf16x8 w;
    w[0] = (__bf16)(a.x * SQRT_CSCALE); w[1] = (__bf16)(a.y * SQRT_CSCALE);
    w[2] = (__bf16)(a.z * SQRT_CSCALE); w[3] = (__bf16)(a.w * SQRT_CSCALE);
    w[4] = (__bf16)(b.x * SQRT_CSCALE); w[5] = (__bf16)(b.y * SQRT_CSCALE);
    w[6] = (__bf16)(b.z * SQRT_CSCALE); w[7] = (__bf16)(b.w * SQRT_CSCALE);
    *(bf16x8*)(out + i) = w;
}

// ---------------- kernel 1: fused GEMM + log2-sum-exp2 partials ----------------
// grid = 32 rowblocks x 16 colsplits = 512 blocks (2/CU), 256 threads (4 waves).
// block: rows [rbk*128, +128), cols [q*256, +256) as 8 tiles of 32 cols x K512.
__global__ __launch_bounds__(256, 2) void jl_main(const __bf16* __restrict__ rb,
                                                  float* __restrict__ pm,
                                                  float* __restrict__ ps,
                                                  float* __restrict__ pos) {
    // 2 buffers x 32 rows x 1KB, row-major with XOR-swizzled 16B chunks
    __shared__ __align__(16) char smem[2][32][1024];

    const int rbk  = blockIdx.x >> 4;   // 0..31
    const int q    = blockIdx.x & 15;   // 0..15
    const int wave = threadIdx.x >> 6;
    const int lane = threadIdx.x & 63;

    const int row0 = rbk * BM + wave * 32;   // wave's first row (32 rows)
    const int col0 = q * 256;
    const int lrow = lane & 15;
    const int lk   = lane >> 4;
    const int swz  = (lrow & 7) << 4;        // read-side XOR (byte units)

    // A fragments, two 16-row halves: 32 x bf16x8 = 128 VGPR (needs (256,2))
    bf16x8 afA[16], afB[16];
    {
        const __bf16* arow = rb + (size_t)(row0 + lrow) * DDIM + lk * 8;
        #pragma unroll
        for (int kb = 0; kb < 16; ++kb) {
            afA[kb] = *(const bf16x8*)(arow + kb * 32);
            afB[kb] = *(const bf16x8*)(arow + 16 * DDIM + kb * 32);
        }
    }

    // coalesced B staging: wave w stages rows 8w..8w+7 of the 32-row tile.
    // per-lane global byte = row_base + (lane*16 ^ ((row&7)<<4))  [same XOR as read]
#define STAGE(J)                                                               \
    do {                                                                       \
        _Pragma("unroll")                                                      \
        for (int i_ = 0; i_ < 8; ++i_) {                                       \
            const int rl_ = wave * 8 + i_;                                     \
            const char* g_ = (const char*)(rb + (size_t)(col0 + (J) * 32 + rl_) * DDIM) \
                             + ((lane * 16) ^ ((rl_ & 7) << 4));               \
            GLOAD_LDS16(g_, &smem[(J) & 1][rl_][0]);                           \
        }                                                                      \
    } while (0)

    STAGE(0);

    float m[2][4], s[2][4];
    #pragma unroll
    for (int h = 0; h < 2; ++h)
        #pragma unroll
        for (int r = 0; r < 4; ++r) { m[h][r] = NEG_BIG; s[h][r] = 0.0f; }

    for (int jt = 0; jt < NT; ++jt) {
        // race-free 2-phase: drain own stage loads, sync, then prefetch next
        asm volatile("s_waitcnt vmcnt(0)" ::: "memory");
        __builtin_amdgcn_s_barrier();
        __builtin_amdgcn_sched_barrier(0);
        if (jt + 1 < NT) STAGE(jt + 1);

        const int cb = jt & 1;

        f32x4 a00 = {0.f,0.f,0.f,0.f}, a01 = {0.f,0.f,0.f,0.f};
        f32x4 a10 = {0.f,0.f,0.f,0.f}, a11 = {0.f,0.f,0.f,0.f};
        __builtin_amdgcn_s_setprio(1);
        #pragma unroll
        for (int kb = 0; kb < 16; ++kb) {
            // B[col = n*16+lrow][k = kb*32+lk*8], swizzled
            bf16x8 b0 = *(const bf16x8*)(&smem[cb][lrow][0]      + ((kb * 64 + lk * 16) ^ swz));
            bf16x8 b1 = *(const bf16x8*)(&smem[cb][16 + lrow][0] + ((kb * 64 + lk * 16) ^ swz));
            a00 = MFMA16(afA[kb], b0, a00);
            a10 = MFMA16(afB[kb], b0, a10);
            a01 = MFMA16(afA[kb], b1, a01);
            a11 = MFMA16(afB[kb], b1, a11);
        }
        __builtin_amdgcn_s_setprio(0);

        // y[h][n]: row = row0 + h*16 + 4*lk + r,  col = ctile + n*16 + lrow
        f32x4 y[2][2] = {{a00, a01}, {a10, a11}};
        const int ctile = col0 + jt * 32;   // wave-uniform

        // positive-pair tile (uniform, rare): partner of row i is i^2048
        if (ctile == (row0 ^ 2048)) {
            #pragma unroll
            for (int h = 0; h < 2; ++h)
                #pragma unroll
                for (int r = 0; r < 4; ++r)
                    if (lrow == 4 * lk + r)
                        pos[row0 + h * 16 + 4 * lk + r] = y[h][h][r];
        }

        if (ctile == row0) {
            // diagonal tile (1 per wave): mask col==row then full online update
            #pragma unroll
            for (int h = 0; h < 2; ++h)
                #pragma unroll
                for (int r = 0; r < 4; ++r) {
                    if (lrow == 4 * lk + r) y[h][h][r] = NEG_BIG;
                    float y0 = y[h][0][r], y1 = y[h][1][r];
                    float mn = fmaxf(m[h][r], fmaxf(y0, y1));
                    s[h][r] = s[h][r] * __builtin_amdgcn_exp2f(m[h][r] - mn)
                            + __builtin_amdgcn_exp2f(y0 - mn)
                            + __builtin_amdgcn_exp2f(y1 - mn);
                    m[h][r] = mn;
                }
        } else {
            float t[2][2][4];
            float dmax = NEG_BIG;
            #pragma unroll
            for (int h = 0; h < 2; ++h)
                #pragma unroll
                for (int n = 0; n < 2; ++n)
                    #pragma unroll
                    for (int r = 0; r < 4; ++r) {
                        t[h][n][r] = y[h][n][r] - m[h][r];
                        dmax = fmaxf(dmax, t[h][n][r]);
                    }
            if (__any(dmax > THR)) {
                #pragma unroll
                for (int h = 0; h < 2; ++h)
                    #pragma unroll
                    for (int r = 0; r < 4; ++r) {
                        float y0 = y[h][0][r], y1 = y[h][1][r];
                        float mn = fmaxf(m[h][r], fmaxf(y0, y1));
                        s[h][r] = s[h][r] * __builtin_amdgcn_exp2f(m[h][r] - mn)
                                + __builtin_amdgcn_exp2f(y0 - mn)
                                + __builtin_amdgcn_exp2f(y1 - mn);
                        m[h][r] = mn;
                    }
            } else {
                #pragma unroll
                for (int h = 0; h < 2; ++h)
                    #pragma unroll
                    for (int r = 0; r < 4; ++r)
                        s[h][r] += __builtin_amdgcn_exp2f(t[h][0][r])
                                 + __builtin_amdgcn_exp2f(t[h][1][r]);
            }
        }
    }
#undef STAGE

    // merge (m,s) across the 16 lanes of each row group, write partials
    #pragma unroll
    for (int h = 0; h < 2; ++h)
        #pragma unroll
        for (int r = 0; r < 4; ++r) {
            float mm = m[h][r], ss = s[h][r];
            #pragma unroll
            for (int off = 1; off < 16; off <<= 1) {
                float mo = __shfl_xor(mm, off, 64);
                float so = __shfl_xor(ss, off, 64);
                float mn = fmaxf(mm, mo);
                ss = ss * __builtin_amdgcn_exp2f(mm - mn)
                   + so * __builtin_amdgcn_exp2f(mo - mn);
                mm = mn;
            }
            if (lrow == 0) {
                const int grow = row0 + 16 * h + 4 * lk + r;
                pm[grow * NSPLIT + q] = mm;
                ps[grow * NSPLIT + q] = ss;
            }
        }
}

// ---------------- kernel 2a: per-row loss + per-block partial sum ----------------
__global__ void jl_rowloss(const float* __restrict__ pm, const float* __restrict__ ps,
                           const float* __restrict__ pos, float* __restrict__ part) {
    __shared__ float red[256];
    const int t = threadIdx.x;
    const int row = blockIdx.x * 256 + t;
    float mb = NEG_BIG;
    #pragma unroll
    for (int qq = 0; qq < NSPLIT; ++qq) mb = fmaxf(mb, pm[row * NSPLIT + qq]);
    float st = 0.0f;
    #pragma unroll
    for (int qq = 0; qq < NSPLIT; ++qq)
        st += ps[row * NSPLIT + qq] * __builtin_amdgcn_exp2f(pm[row * NSPLIT + qq] - mb);
    red[t] = mb + __builtin_amdgcn_logf(st) - pos[row];
    __syncthreads();
    for (int off = 128; off > 0; off >>= 1) {
        if (t < off) red[t] += red[t + off];
        __syncthreads();
    }
    if (t == 0) part[blockIdx.x] = red[0];
}

// ---------------- kernel 2b: final reduce ----------------
__global__ void jl_final(const float* __restrict__ part, float* __restrict__ out) {
    const int t = threadIdx.x;
    float v = (t < NROWS / 256) ? part[t] : 0.0f;
    #pragma unroll
    for (int off = 1; off < 16; off <<= 1) v += __shfl_xor(v, off, 64);
    if (t == 0) out[0] = v * (LN2 / (float)NROWS);
}

extern "C" void kernel_launch(void* const* d_in, const int* in_sizes, int n_in,
                              void* d_out, int out_size, void* d_ws, size_t ws_size,
                              hipStream_t stream) {
    const float* rep = (const float*)d_in[0];
    float* out = (float*)d_out;

    __bf16* rbuf = (__bf16*)d_ws;
    float*  pm   = (float*)(rbuf + (size_t)NROWS * DDIM);
    float*  ps   = pm + NROWS * NSPLIT;
    float*  pos  = ps + NROWS * NSPLIT;
    float*  part = pos + NROWS;

    jl_cvt<<<(NROWS * DDIM) / (256 * 8), 256, 0, stream>>>(rep, rbuf);
    jl_main<<<32 * NSPLIT, 256, 0, stream>>>(rbuf, pm, ps, pos);
    jl_rowloss<<<NROWS / 256, 256, 0, stream>>>(pm, ps, pos, part);
    jl_final<<<1, 64, 0, stream>>>(part, out);
}